// Round 2
// baseline (60937.891 us; speedup 1.0000x reference)
//
#include <hip/hip_runtime.h>

// LSTM autoencoder, persistent kernel v2.
// 256 blocks x 1024 threads (16 waves/CU, all co-resident).
// Per phase: block tile = 32 d x 8 b x 4-way K-split; LDS-staged X; packed
// gate-interleaved weights (Wp[d][k][g]) when ws_size permits.

#define Bsz 128
#define Tsz 128
#define Fsz 128
#define Dsz 512
#define ND  2048
#define NBLK 256
#define NTHR 1024

// ---- ws layout (float offsets) ----
#define OFF_FLAG 2048                    // 32 counters * 64 uints before this
#define OFF_H0   4096
#define OFF_C0   (OFF_H0 + Bsz*Dsz)
#define OFF_H1   (OFF_C0 + Bsz*Dsz)
#define OFF_C1   (OFF_H1 + Bsz*Dsz)
#define OFF_HM   (OFF_C1 + Bsz*Dsz)
#define OFF_CM   (OFF_HM + Bsz*Dsz)
#define OFF_WEND (OFF_CM + Bsz*Dsz)      // 397312
// strided (fallback) mode
#define OFF_S_WSUM  OFF_WEND
#define OFF_S_WDECA (OFF_S_WSUM + Dsz*ND)
#define OFF_S_BF    (OFF_S_WDECA + Dsz*ND)
#define WS_STRIDED_FLOATS (OFF_S_BF + ND)
// packed mode
#define OFF_P_EW0   OFF_WEND
#define OFF_P_EU0   (OFF_P_EW0 + Fsz*ND)
#define OFF_P_WSUM  (OFF_P_EU0 + Dsz*ND)
#define OFF_P_WDECA (OFF_P_WSUM + Dsz*ND)
#define OFF_P_DW0   (OFF_P_WDECA + Dsz*ND)
#define OFF_P_DU0   (OFF_P_DW0 + Fsz*ND)
#define OFF_P_DW1   (OFF_P_DU0 + Dsz*ND)
#define OFF_P_DU1   (OFF_P_DW1 + Dsz*ND)
#define OFF_P_BF    (OFF_P_DU1 + Dsz*ND)
#define WS_PACKED_FLOATS (OFF_P_BF + ND)

__device__ __forceinline__ float sigf(float x) {
    return 1.0f / (1.0f + __expf(-x));
}

// ---- hierarchical grid barrier ----
// 32 counters (256B apart); block0 wave0 sums them, then releases a flag.
__device__ __forceinline__ void gbar(unsigned* cnt, unsigned* flag, unsigned epoch) {
    __syncthreads();
    const int tid = threadIdx.x;
    if (tid == 0) {
        __threadfence();
        __hip_atomic_fetch_add(&cnt[(blockIdx.x & 31) * 64], 1u,
                               __ATOMIC_RELEASE, __HIP_MEMORY_SCOPE_AGENT);
    }
    if (blockIdx.x == 0 && tid < 64) {
        const unsigned target = epoch * (unsigned)NBLK;
        for (;;) {
            unsigned v = 0;
            if (tid < 32)
                v = __hip_atomic_load(&cnt[tid * 64], __ATOMIC_ACQUIRE,
                                      __HIP_MEMORY_SCOPE_AGENT);
            #pragma unroll
            for (int off = 16; off; off >>= 1) v += __shfl_down(v, off, 64);
            v = __shfl(v, 0, 64);
            if (v >= target) break;
            __builtin_amdgcn_s_sleep(1);
        }
        if (tid == 0) {
            __threadfence();
            __hip_atomic_store(flag, epoch, __ATOMIC_RELEASE, __HIP_MEMORY_SCOPE_AGENT);
        }
    }
    if (tid == 0) {
        while (__hip_atomic_load(flag, __ATOMIC_ACQUIRE, __HIP_MEMORY_SCOPE_AGENT) < epoch)
            __builtin_amdgcn_s_sleep(1);
    }
    __syncthreads();
}

// ---- LDS staging: 8 rows of klen floats from src (row stride ld) ----
// kshift = log2(klen); klen in {128, 512}.
__device__ __forceinline__ void stage(float* XL, int ktot, const float* src, int ld,
                                      int klen, int kshift, int dstoff, int bg) {
    const int n4 = (klen * 8) >> 2;
    const int c4shift = kshift - 2;
    const int c4mask = (klen >> 2) - 1;
    for (int i = threadIdx.x; i < n4; i += NTHR) {
        const int row = i >> c4shift;
        const int c4 = i & c4mask;
        float4 v = *(const float4*)(src + (size_t)(bg * 8 + row) * ld + (c4 << 2));
        *(float4*)(XL + row * ktot + dstoff + (c4 << 2)) = v;
    }
}

// ---- strided accumulate (original weight layout [k][2048], gates blocked) ----
__device__ __forceinline__ void accumS(float& zi, float& zf, float& zg, float& zo,
                                       const float* xrow, int kbeg, int klen,
                                       const float* W, int dcol) {
    const float* wp = W + (size_t)kbeg * ND + dcol;
    const float* xp = xrow + kbeg;
    for (int k = 0; k < klen; k += 4) {
        float4 xv = *(const float4*)(xp + k);
        zi += xv.x*wp[0]     + xv.y*wp[ND]       + xv.z*wp[2*ND]       + xv.w*wp[3*ND];
        zf += xv.x*wp[Dsz]   + xv.y*wp[ND+Dsz]   + xv.z*wp[2*ND+Dsz]   + xv.w*wp[3*ND+Dsz];
        zg += xv.x*wp[2*Dsz] + xv.y*wp[ND+2*Dsz] + xv.z*wp[2*ND+2*Dsz] + xv.w*wp[3*ND+2*Dsz];
        zo += xv.x*wp[3*Dsz] + xv.y*wp[ND+3*Dsz] + xv.z*wp[2*ND+3*Dsz] + xv.w*wp[3*ND+3*Dsz];
        wp += 4 * ND;
    }
}

// ---- packed accumulate: Wp[(d*K + k)*4 + g]; per-lane sequential 64B lines ----
__device__ __forceinline__ void accumP(float& zi, float& zf, float& zg, float& zo,
                                       const float* xrow, int kbeg, int klen,
                                       const float* Wp, int K, int dcol) {
    const float4* wp = (const float4*)Wp + (size_t)dcol * K + kbeg;
    const float* xp = xrow + kbeg;
    for (int k = 0; k < klen; k += 4) {
        float4 xv = *(const float4*)(xp + k);
        float4 w0 = wp[0], w1 = wp[1], w2 = wp[2], w3 = wp[3];
        zi += xv.x*w0.x + xv.y*w1.x + xv.z*w2.x + xv.w*w3.x;
        zf += xv.x*w0.y + xv.y*w1.y + xv.z*w2.y + xv.w*w3.y;
        zg += xv.x*w0.z + xv.y*w1.z + xv.z*w2.z + xv.w*w3.z;
        zo += xv.x*w0.w + xv.y*w1.w + xv.z*w2.w + xv.w*w3.w;
        wp += 4;
    }
}

// ---- one LSTM cell phase ----
template<bool PACKED>
__device__ void cell_phase(float* XL, float* RED, float* ORED,
                           const float* x0, int ld0, int K0, int k0shift, const float* W0,
                           const float* x1, const float* W1,
                           const float* bias, const float* cprev,
                           float* hout, float* cout,
                           const float* dwm, const float* dbv, float* outp, int tt)
{
    const int tid = threadIdx.x;
    const int dg = blockIdx.x & 15;
    const int bg = blockIdx.x >> 4;
    const int Ktot = x1 ? (K0 + Dsz) : K0;

    stage(XL, Ktot, x0, ld0, K0, k0shift, 0, bg);
    if (x1) stage(XL, Ktot, x1, Dsz, Dsz, 9, K0, bg);
    __syncthreads();

    const int d = tid & 31;
    const int s = (tid >> 5) & 3;
    const int b = tid >> 7;
    const int dcol = dg * 32 + d;
    const float* xrow = XL + b * Ktot;

    float zi = 0.f, zf = 0.f, zg = 0.f, zo = 0.f;
    if (PACKED) {
        accumP(zi, zf, zg, zo, xrow, s * (K0 >> 2), K0 >> 2, W0, K0, dcol);
        if (x1) accumP(zi, zf, zg, zo, xrow + K0, s * (Dsz >> 2), Dsz >> 2, W1, Dsz, dcol);
    } else {
        accumS(zi, zf, zg, zo, xrow, s * (K0 >> 2), K0 >> 2, W0, dcol);
        if (x1) accumS(zi, zf, zg, zo, xrow + K0, s * (Dsz >> 2), Dsz >> 2, W1, dcol);
    }

    ((float4*)RED)[(s * 8 + b) * 32 + d] = make_float4(zi, zf, zg, zo);

    if (outp) {  // fused out-row partial: out_{t-1} = h_{t-1} @ dense_W (+db)
        const int os = tid & 15, of = (tid >> 4) & 7, ob = tid >> 7;
        const int fcol = dg * 8 + of;
        const float* xr = XL + ob * Ktot + os * 32;
        const float* wp = dwm + (size_t)(os * 32) * Fsz + fcol;
        float acc = 0.f;
        #pragma unroll
        for (int j = 0; j < 32; ++j) acc += xr[j] * wp[(size_t)j * Fsz];
        ORED[(ob * 8 + of) * 16 + os] = acc;
    }
    __syncthreads();

    if (tid < 256) {  // finalize gates for one (b,d)
        const int fb = tid >> 5, fd = tid & 31;
        const float4* R4 = (const float4*)RED;
        float4 r0 = R4[fb * 32 + fd];
        float4 r1 = R4[256 + fb * 32 + fd];
        float4 r2 = R4[512 + fb * 32 + fd];
        float4 r3 = R4[768 + fb * 32 + fd];
        const int dc = dg * 32 + fd;
        const int bgl = bg * 8 + fb;
        float vzi = r0.x + r1.x + r2.x + r3.x + bias[dc];
        float vzf = r0.y + r1.y + r2.y + r3.y + bias[Dsz + dc];
        float vzg = r0.z + r1.z + r2.z + r3.z + bias[2 * Dsz + dc];
        float vzo = r0.w + r1.w + r2.w + r3.w + bias[3 * Dsz + dc];
        float gi = sigf(vzi), gf = sigf(vzf);
        float gg = fmaxf(vzg, 0.f), go = sigf(vzo);
        float c2 = gf * cprev[(size_t)bgl * Dsz + dc] + gi * gg;
        float h2 = go * fmaxf(c2, 0.f);
        hout[(size_t)bgl * Dsz + dc] = h2;
        if (cout) cout[(size_t)bgl * Dsz + dc] = c2;
    } else if (outp && tid >= 512 && tid < 576) {
        const int o = tid - 512, ob = o >> 3, of = o & 7;
        const float* r = ORED + (ob * 8 + of) * 16;
        float acc = 0.f;
        #pragma unroll
        for (int j = 0; j < 16; ++j) acc += r[j];
        const int fcol = dg * 8 + of;
        outp[((size_t)(bg * 8 + ob) * Tsz + tt) * Fsz + fcol] = acc + dbv[fcol];
    }
}

// ---- standalone out row (t=127 -> row 0) ----
__device__ void out_only(float* XL, float* ORED, const float* h,
                         const float* dwm, const float* dbv, float* outp, int tt)
{
    const int tid = threadIdx.x;
    const int dg = blockIdx.x & 15;
    const int bg = blockIdx.x >> 4;
    stage(XL, Dsz, h, Dsz, Dsz, 9, 0, bg);
    __syncthreads();
    {
        const int os = tid & 15, of = (tid >> 4) & 7, ob = tid >> 7;
        const int fcol = dg * 8 + of;
        const float* xr = XL + ob * Dsz + os * 32;
        const float* wp = dwm + (size_t)(os * 32) * Fsz + fcol;
        float acc = 0.f;
        #pragma unroll
        for (int j = 0; j < 32; ++j) acc += xr[j] * wp[(size_t)j * Fsz];
        ORED[(ob * 8 + of) * 16 + os] = acc;
    }
    __syncthreads();
    if (tid < 64) {
        const int ob = tid >> 3, of = tid & 7;
        const float* r = ORED + (ob * 8 + of) * 16;
        float acc = 0.f;
        #pragma unroll
        for (int j = 0; j < 16; ++j) acc += r[j];
        const int fcol = dg * 8 + of;
        outp[((size_t)(bg * 8 + ob) * Tsz + tt) * Fsz + fcol] = acc + dbv[fcol];
    }
}

// ---- P0 helpers ----
__device__ void pack_gate(float* dst, const float* src, int K, int kshift, int gid) {
    const int total = K * Dsz;
    for (int u = gid; u < total; u += NBLK * NTHR) {
        const int dd = u >> kshift;
        const int k = u & (K - 1);
        const float* sp = src + (size_t)k * ND + dd;
        ((float4*)dst)[u] = make_float4(sp[0], sp[Dsz], sp[2 * Dsz], sp[3 * Dsz]);
    }
}
__device__ void pack_wsum(float* dst, const float* a, const float* b, int gid) {
    for (int u = gid; u < Dsz * Dsz; u += NBLK * NTHR) {
        const int dd = u >> 9, k = u & 511;
        const float* pa = a + (size_t)k * ND + dd;
        const float* pb = b + (size_t)k * ND + dd;
        ((float4*)dst)[u] = make_float4(pa[0] + pb[0], pa[Dsz] + pb[Dsz],
                                        pa[2*Dsz] + pb[2*Dsz], pa[3*Dsz] + pb[3*Dsz]);
    }
}
__device__ void pack_wdeca(float* dst, const float* dU0, const float* dW0,
                           const float* dw, int gid) {
    for (int u = gid; u < Dsz * Dsz; u += NBLK * NTHR) {
        const int dd = u >> 9, k = u & 511;
        const float* pu = dU0 + (size_t)k * ND + dd;
        float a0 = pu[0], a1 = pu[Dsz], a2 = pu[2*Dsz], a3 = pu[3*Dsz];
        const float* dwr = dw + k * Fsz;
        for (int j = 0; j < Fsz; ++j) {
            const float wv = dwr[j];
            const float* dr = dW0 + (size_t)j * ND + dd;
            a0 += wv * dr[0]; a1 += wv * dr[Dsz];
            a2 += wv * dr[2*Dsz]; a3 += wv * dr[3*Dsz];
        }
        ((float4*)dst)[u] = make_float4(a0, a1, a2, a3);
    }
}

template<bool PACKED>
__global__ void __launch_bounds__(NTHR)
lstm_ae_kernel(const float* enc_in, const float* dec_in,
               const float* eW0, const float* eU0, const float* eb0,
               const float* eW1, const float* eU1, const float* eb1,
               const float* dW0, const float* dU0, const float* db0,
               const float* dW1, const float* dU1, const float* db1,
               const float* dw, const float* db_, float* out, float* ws)
{
    __shared__ float XL[8 * 1024];
    __shared__ float RED[4096];
    __shared__ float ORED[1024];

    unsigned* cnt = (unsigned*)ws;
    unsigned* flag = (unsigned*)(ws + OFF_FLAG);
    float* H[2] = { ws + OFF_H0, ws + OFF_H1 };
    float* C[2] = { ws + OFF_C0, ws + OFF_C1 };
    float* HM = ws + OFF_HM;
    float* CM = ws + OFF_CM;

    const int gid = blockIdx.x * NTHR + threadIdx.x;
    unsigned ep = 0;

    const float *pEW0, *pEU0, *pWSUM, *pWDECA, *pDW0, *pDU0, *pDW1, *pDU1, *pBF;

    // ---- P0: fold + (optionally) pack weights ----
    if (PACKED) {
        pack_gate(ws + OFF_P_EW0, eW0, Fsz, 7, gid);
        pack_gate(ws + OFF_P_EU0, eU0, Dsz, 9, gid);
        pack_wsum(ws + OFF_P_WSUM, eW1, eU1, gid);
        pack_wdeca(ws + OFF_P_WDECA, dU0, dW0, dw, gid);
        pack_gate(ws + OFF_P_DW0, dW0, Fsz, 7, gid);
        pack_gate(ws + OFF_P_DU0, dU0, Dsz, 9, gid);
        pack_gate(ws + OFF_P_DW1, dW1, Dsz, 9, gid);
        pack_gate(ws + OFF_P_DU1, dU1, Dsz, 9, gid);
        if (gid < ND) {
            float acc = db0[gid];
            for (int j = 0; j < Fsz; ++j) acc += db_[j] * dW0[(size_t)j * ND + gid];
            (ws + OFF_P_BF)[gid] = acc;
        }
        pEW0 = ws + OFF_P_EW0; pEU0 = ws + OFF_P_EU0; pWSUM = ws + OFF_P_WSUM;
        pWDECA = ws + OFF_P_WDECA; pDW0 = ws + OFF_P_DW0; pDU0 = ws + OFF_P_DU0;
        pDW1 = ws + OFF_P_DW1; pDU1 = ws + OFF_P_DU1; pBF = ws + OFF_P_BF;
    } else {
        for (int i = gid; i < Dsz * ND; i += NBLK * NTHR)
            (ws + OFF_S_WSUM)[i] = eW1[i] + eU1[i];
        for (int u = gid; u < Dsz * ND; u += NBLK * NTHR) {
            const int k = u >> 11, col = u & (ND - 1);
            float acc = dU0[u];
            const float* dwr = dw + k * Fsz;
            for (int j = 0; j < Fsz; ++j) acc += dwr[j] * dW0[(size_t)j * ND + col];
            (ws + OFF_S_WDECA)[u] = acc;
        }
        if (gid < ND) {
            float acc = db0[gid];
            for (int j = 0; j < Fsz; ++j) acc += db_[j] * dW0[(size_t)j * ND + gid];
            (ws + OFF_S_BF)[gid] = acc;
        }
        pEW0 = eW0; pEU0 = eU0; pWSUM = ws + OFF_S_WSUM; pWDECA = ws + OFF_S_WDECA;
        pDW0 = dW0; pDU0 = dU0; pDW1 = dW1; pDU1 = dU1; pBF = ws + OFF_S_BF;
    }
    gbar(cnt, flag, ++ep);

    int cur = 0;

    // ---- encoder ----
    for (int t = 0; t < Tsz; ++t) {
        cell_phase<PACKED>(XL, RED, ORED, enc_in + (size_t)t * Fsz, Tsz * Fsz, Fsz, 7, pEW0,
                           H[cur], pEU0, eb0, C[cur], HM, CM,
                           nullptr, nullptr, nullptr, 0);
        gbar(cnt, flag, ++ep);
        cell_phase<PACKED>(XL, RED, ORED, HM, Dsz, Dsz, 9, pWSUM,
                           nullptr, nullptr, eb1, CM, H[cur ^ 1], C[cur ^ 1],
                           nullptr, nullptr, nullptr, 0);
        gbar(cnt, flag, ++ep);
        cur ^= 1;
    }

    // ---- decoder t=0 ----
    cell_phase<PACKED>(XL, RED, ORED, dec_in, Tsz * Fsz, Fsz, 7, pDW0,
                       H[cur], pDU0, db0, C[cur], HM, nullptr,
                       nullptr, nullptr, nullptr, 0);
    gbar(cnt, flag, ++ep);
    cell_phase<PACKED>(XL, RED, ORED, HM, Dsz, Dsz, 9, pDW1,
                       H[cur], pDU1, db1, C[cur], H[cur ^ 1], C[cur ^ 1],
                       nullptr, nullptr, nullptr, 0);
    gbar(cnt, flag, ++ep);
    cur ^= 1;

    // ---- decoder t=1..127 (folded input; emit out_{t-1} at row T-t) ----
    for (int t = 1; t < Tsz; ++t) {
        cell_phase<PACKED>(XL, RED, ORED, H[cur], Dsz, Dsz, 9, pWDECA,
                           nullptr, nullptr, pBF, C[cur], HM, nullptr,
                           dw, db_, out, Tsz - t);
        gbar(cnt, flag, ++ep);
        cell_phase<PACKED>(XL, RED, ORED, HM, Dsz, Dsz, 9, pDW1,
                           H[cur], pDU1, db1, C[cur], H[cur ^ 1], C[cur ^ 1],
                           nullptr, nullptr, nullptr, 0);
        gbar(cnt, flag, ++ep);
        cur ^= 1;
    }

    // ---- final out row ----
    out_only(XL, ORED, H[cur], dw, db_, out, 0);
}

extern "C" void kernel_launch(void* const* d_in, const int* in_sizes, int n_in,
                              void* d_out, int out_size, void* d_ws, size_t ws_size,
                              hipStream_t stream) {
    (void)in_sizes; (void)n_in; (void)out_size;
    const float* enc_in = (const float*)d_in[0];
    const float* dec_in = (const float*)d_in[1];
    const float* eW0 = (const float*)d_in[2];
    const float* eU0 = (const float*)d_in[3];
    const float* eb0 = (const float*)d_in[4];
    const float* eW1 = (const float*)d_in[5];
    const float* eU1 = (const float*)d_in[6];
    const float* eb1 = (const float*)d_in[7];
    const float* dW0 = (const float*)d_in[8];
    const float* dU0 = (const float*)d_in[9];
    const float* db0 = (const float*)d_in[10];
    const float* dW1 = (const float*)d_in[11];
    const float* dU1 = (const float*)d_in[12];
    const float* db1 = (const float*)d_in[13];
    const float* dw  = (const float*)d_in[14];
    const float* db_ = (const float*)d_in[15];
    float* out = (float*)d_out;
    float* ws = (float*)d_ws;

    // zero: barrier counters/flag + H0 + C0
    hipMemsetAsync(d_ws, 0, (size_t)(OFF_H0 + 2 * Bsz * Dsz) * sizeof(float), stream);

    const bool packed = ws_size >= (size_t)WS_PACKED_FLOATS * sizeof(float);
    if (packed)
        lstm_ae_kernel<true><<<NBLK, NTHR, 0, stream>>>(
            enc_in, dec_in, eW0, eU0, eb0, eW1, eU1, eb1,
            dW0, dU0, db0, dW1, dU1, db1, dw, db_, out, ws);
    else
        lstm_ae_kernel<false><<<NBLK, NTHR, 0, stream>>>(
            enc_in, dec_in, eW0, eU0, eb0, eW1, eU1, eb1,
            dW0, dU0, db0, dW1, dU1, db1, dw, db_, out, ws);
}

// Round 3
// 49289.038 us; speedup vs baseline: 1.2363x; 1.2363x over previous
//
#include <hip/hip_runtime.h>

// LSTM autoencoder v3: 8 independent sample-groups (16 samples each), 32 blocks
// per group, per-group 32-wide barriers (store-arrive + vector-poll).
// group = blockIdx&7 => group's blocks share one XCD (perf heuristic only;
// correctness uses agent-scope atomics + threadfence regardless of placement).
// 256 blocks x 1024 threads, ~86KB LDS => 1 block/CU, all co-resident.

#define Bsz 128
#define Tsz 128
#define Fsz 128
#define Dsz 512
#define ND  2048
#define NBLK 256
#define NTHR 1024
#define MPG 32   // blocks (members) per group
#define BPG 16   // samples per group
#define DPM 16   // d-columns per member

// ---- ws layout (float offsets) ----
#define OFF_H0   4096
#define OFF_C0   (OFF_H0 + Bsz*Dsz)
#define OFF_H1   (OFF_C0 + Bsz*Dsz)
#define OFF_C1   (OFF_H1 + Bsz*Dsz)
#define OFF_HM   (OFF_C1 + Bsz*Dsz)
#define OFF_CM   (OFF_HM + Bsz*Dsz)
#define OFF_WEND (OFF_CM + Bsz*Dsz)
#define OFF_S_WSUM  OFF_WEND
#define OFF_S_WDECA (OFF_S_WSUM + Dsz*ND)
#define OFF_S_BF    (OFF_S_WDECA + Dsz*ND)
#define WS_STRIDED_FLOATS (OFF_S_BF + ND)
#define OFF_P_EW0   OFF_WEND
#define OFF_P_EU0   (OFF_P_EW0 + Fsz*ND)
#define OFF_P_WSUM  (OFF_P_EU0 + Dsz*ND)
#define OFF_P_WDECA (OFF_P_WSUM + Dsz*ND)
#define OFF_P_DW0   (OFF_P_WDECA + Dsz*ND)
#define OFF_P_DU0   (OFF_P_DW0 + Fsz*ND)
#define OFF_P_DW1   (OFF_P_DU0 + Dsz*ND)
#define OFF_P_DU1   (OFF_P_DW1 + Dsz*ND)
#define OFF_P_BF    (OFF_P_DU1 + Dsz*ND)
#define OFF_P_DWT   (OFF_P_BF + ND)
#define WS_PACKED_FLOATS (OFF_P_DWT + Dsz*Fsz)

#define XSTR_MAX 1028   // max Ktot (1024) + 4 pad

__device__ __forceinline__ float sigf(float x) {
    return 1.0f / (1.0f + __expf(-x));
}

__device__ __forceinline__ void gbar_group(unsigned* slots, int grp, int mem, unsigned ep) {
    __syncthreads();
    const int tid = threadIdx.x;
    if (tid == 0) {
        __threadfence();
        __hip_atomic_store(&slots[(grp * MPG + mem) * 16], ep,
                           __ATOMIC_RELEASE, __HIP_MEMORY_SCOPE_AGENT);
    }
    if (tid < 64) {
        unsigned* base = &slots[grp * MPG * 16];
        for (;;) {
            unsigned v = ep;
            if (tid < MPG)
                v = __hip_atomic_load(&base[tid * 16], __ATOMIC_ACQUIRE,
                                      __HIP_MEMORY_SCOPE_AGENT);
            if (__all(v >= ep)) break;
            __builtin_amdgcn_s_sleep(2);
        }
    }
    __syncthreads();
}

__device__ __forceinline__ void gbar_all(unsigned* slots, int grp, int mem, unsigned ep) {
    __syncthreads();
    const int tid = threadIdx.x;
    if (tid == 0) {
        __threadfence();
        __hip_atomic_store(&slots[(grp * MPG + mem) * 16], ep,
                           __ATOMIC_RELEASE, __HIP_MEMORY_SCOPE_AGENT);
    }
    if (tid < 64) {
        for (;;) {
            unsigned mn = ~0u;
            #pragma unroll
            for (int q = 0; q < 4; ++q) {
                unsigned v = __hip_atomic_load(&slots[(tid * 4 + q) * 16],
                                               __ATOMIC_ACQUIRE, __HIP_MEMORY_SCOPE_AGENT);
                mn = min(mn, v);
            }
            if (__all(mn >= ep)) break;
            __builtin_amdgcn_s_sleep(2);
        }
    }
    __syncthreads();
}

__device__ __forceinline__ void stage(float* XL, int xstr, int dstoff,
                                      const float* src, int ld, int klen,
                                      int c4shift, int grp) {
    const int q = klen >> 2;
    const int n4 = q * BPG;
    for (int i = threadIdx.x; i < n4; i += NTHR) {
        const int row = i >> c4shift;
        const int c4 = i & (q - 1);
        float4 v = *(const float4*)(src + (size_t)(grp * BPG + row) * ld + (c4 << 2));
        *(float4*)(XL + row * xstr + dstoff + (c4 << 2)) = v;
    }
}

__device__ __forceinline__ void accumP(float& zi, float& zf, float& zg, float& zo,
                                       const float* xrow, int kbeg, int klen,
                                       const float* Wp, int K, int dcol) {
    const float4* wp = (const float4*)Wp + (size_t)dcol * K + kbeg;
    const float* xp = xrow + kbeg;
    for (int k = 0; k < klen; k += 4) {
        float4 xv = *(const float4*)(xp + k);
        float4 w0 = wp[k], w1 = wp[k + 1], w2 = wp[k + 2], w3 = wp[k + 3];
        zi += xv.x * w0.x + xv.y * w1.x + xv.z * w2.x + xv.w * w3.x;
        zf += xv.x * w0.y + xv.y * w1.y + xv.z * w2.y + xv.w * w3.y;
        zg += xv.x * w0.z + xv.y * w1.z + xv.z * w2.z + xv.w * w3.z;
        zo += xv.x * w0.w + xv.y * w1.w + xv.z * w2.w + xv.w * w3.w;
    }
}

__device__ __forceinline__ void accumS(float& zi, float& zf, float& zg, float& zo,
                                       const float* xrow, int kbeg, int klen,
                                       const float* W, int dcol) {
    const float* wp = W + (size_t)kbeg * ND + dcol;
    const float* xp = xrow + kbeg;
    for (int k = 0; k < klen; k += 4) {
        float4 xv = *(const float4*)(xp + k);
        zi += xv.x*wp[0]     + xv.y*wp[ND]       + xv.z*wp[2*ND]       + xv.w*wp[3*ND];
        zf += xv.x*wp[Dsz]   + xv.y*wp[ND+Dsz]   + xv.z*wp[2*ND+Dsz]   + xv.w*wp[3*ND+Dsz];
        zg += xv.x*wp[2*Dsz] + xv.y*wp[ND+2*Dsz] + xv.z*wp[2*ND+2*Dsz] + xv.w*wp[3*ND+2*Dsz];
        zo += xv.x*wp[3*Dsz] + xv.y*wp[ND+3*Dsz] + xv.z*wp[2*ND+3*Dsz] + xv.w*wp[3*ND+3*Dsz];
        wp += 4 * ND;
    }
}

template<bool PACKED>
__device__ void cell_phase(float* XL, float* RED, float* ORED, int grp, int mem,
                           const float* x0, int ld0, int K0, int c4s0, const float* W0,
                           const float* x1, const float* W1,
                           const float* bias, const float* cprev,
                           float* hout, float* cout,
                           const float* dwx, const float* dbv, float* outp, int tt)
{
    const int tid = threadIdx.x;
    const int Ktot = x1 ? (K0 + Dsz) : K0;
    const int xstr = Ktot + 4;

    stage(XL, xstr, 0, x0, ld0, K0, c4s0, grp);
    if (x1) stage(XL, xstr, K0, x1, Dsz, Dsz, 7, grp);
    __syncthreads();

    const int d = tid & 15;
    const int b = (tid >> 4) & 15;
    const int s = tid >> 8;
    const int dcol = mem * DPM + d;
    const float* xrow = XL + b * xstr;

    float zi = 0.f, zf = 0.f, zg = 0.f, zo = 0.f;
    if (PACKED) {
        accumP(zi, zf, zg, zo, xrow, s * (K0 >> 2), K0 >> 2, W0, K0, dcol);
        if (x1) accumP(zi, zf, zg, zo, xrow + K0, s * (Dsz >> 2), Dsz >> 2, W1, Dsz, dcol);
    } else {
        accumS(zi, zf, zg, zo, xrow, s * (K0 >> 2), K0 >> 2, W0, dcol);
        if (x1) accumS(zi, zf, zg, zo, xrow + K0, s * (Dsz >> 2), Dsz >> 2, W1, dcol);
    }
    ((float4*)RED)[(s * BPG + b) * DPM + d] = make_float4(zi, zf, zg, zo);

    if (outp) {  // partial of out_{t-1} = x0 @ dense_W  (x0 = h_{t-1}, K0=512)
        const int os = tid & 15, f = (tid >> 4) & 3, bl = tid >> 6;
        const int fcol = mem * 4 + f;
        const float* xr = XL + bl * xstr + os * 32;
        float acc = 0.f;
        if (PACKED) {
            const float* wT = dwx + (size_t)fcol * Dsz + os * 32;
            #pragma unroll
            for (int j2 = 0; j2 < 32; ++j2) {
                const int j = (j2 + os * 2) & 31;
                acc += xr[j] * wT[j];
            }
        } else {
            const float* wS = dwx + fcol;
            #pragma unroll
            for (int j2 = 0; j2 < 32; ++j2) {
                const int j = (j2 + os * 2) & 31;
                acc += xr[j] * wS[(size_t)(os * 32 + j) * Fsz];
            }
        }
        ORED[(bl * 4 + f) * 16 + os] = acc;
    }
    __syncthreads();

    if (tid < 256) {
        const int dd = tid & 15, bl = tid >> 4;
        const float4* R4 = (const float4*)RED;
        float4 r0 = R4[bl * DPM + dd];
        float4 r1 = R4[256 + bl * DPM + dd];
        float4 r2 = R4[512 + bl * DPM + dd];
        float4 r3 = R4[768 + bl * DPM + dd];
        const int dc = mem * DPM + dd;
        const int bgl = grp * BPG + bl;
        float vzi = r0.x + r1.x + r2.x + r3.x + bias[dc];
        float vzf = r0.y + r1.y + r2.y + r3.y + bias[Dsz + dc];
        float vzg = r0.z + r1.z + r2.z + r3.z + bias[2 * Dsz + dc];
        float vzo = r0.w + r1.w + r2.w + r3.w + bias[3 * Dsz + dc];
        float gi = sigf(vzi), gf = sigf(vzf);
        float gg = fmaxf(vzg, 0.f), go = sigf(vzo);
        float c2 = gf * cprev[(size_t)bgl * Dsz + dc] + gi * gg;
        float h2 = go * fmaxf(c2, 0.f);
        hout[(size_t)bgl * Dsz + dc] = h2;
        if (cout) cout[(size_t)bgl * Dsz + dc] = c2;
    } else if (outp && tid >= 256 && tid < 320) {
        const int o = tid - 256, bl = o >> 2, f = o & 3;
        const float* r = ORED + (bl * 4 + f) * 16;
        float acc = 0.f;
        #pragma unroll
        for (int j = 0; j < 16; ++j) acc += r[j];
        const int fcol = mem * 4 + f;
        outp[((size_t)(grp * BPG + bl) * Tsz + tt) * Fsz + fcol] = acc + dbv[fcol];
    }
}

template<bool PACKED>
__device__ void out_only(float* XL, float* ORED, int grp, int mem,
                         const float* h, const float* dwx, const float* dbv,
                         float* outp, int tt)
{
    const int tid = threadIdx.x;
    const int xstr = Dsz + 4;
    stage(XL, xstr, 0, h, Dsz, Dsz, 7, grp);
    __syncthreads();
    {
        const int os = tid & 15, f = (tid >> 4) & 3, bl = tid >> 6;
        const int fcol = mem * 4 + f;
        const float* xr = XL + bl * xstr + os * 32;
        float acc = 0.f;
        if (PACKED) {
            const float* wT = dwx + (size_t)fcol * Dsz + os * 32;
            #pragma unroll
            for (int j2 = 0; j2 < 32; ++j2) {
                const int j = (j2 + os * 2) & 31;
                acc += xr[j] * wT[j];
            }
        } else {
            const float* wS = dwx + fcol;
            #pragma unroll
            for (int j2 = 0; j2 < 32; ++j2) {
                const int j = (j2 + os * 2) & 31;
                acc += xr[j] * wS[(size_t)(os * 32 + j) * Fsz];
            }
        }
        ORED[(bl * 4 + f) * 16 + os] = acc;
    }
    __syncthreads();
    if (tid < 64) {
        const int bl = tid >> 2, f = tid & 3;
        const float* r = ORED + (bl * 4 + f) * 16;
        float acc = 0.f;
        #pragma unroll
        for (int j = 0; j < 16; ++j) acc += r[j];
        const int fcol = mem * 4 + f;
        outp[((size_t)(grp * BPG + bl) * Tsz + tt) * Fsz + fcol] = acc + dbv[fcol];
    }
}

__device__ void pack_gate(float* dst, const float* src, int K, int kshift, int gid) {
    const int total = K * Dsz;
    for (int u = gid; u < total; u += NBLK * NTHR) {
        const int dd = u >> kshift;
        const int k = u & (K - 1);
        const float* sp = src + (size_t)k * ND + dd;
        ((float4*)dst)[u] = make_float4(sp[0], sp[Dsz], sp[2 * Dsz], sp[3 * Dsz]);
    }
}
__device__ void pack_wsum(float* dst, const float* a, const float* b, int gid) {
    for (int u = gid; u < Dsz * Dsz; u += NBLK * NTHR) {
        const int dd = u >> 9, k = u & 511;
        const float* pa = a + (size_t)k * ND + dd;
        const float* pb = b + (size_t)k * ND + dd;
        ((float4*)dst)[u] = make_float4(pa[0] + pb[0], pa[Dsz] + pb[Dsz],
                                        pa[2*Dsz] + pb[2*Dsz], pa[3*Dsz] + pb[3*Dsz]);
    }
}
__device__ void pack_wdeca_p(float* dst, const float* dU0, const float* dW0,
                             const float* dw, int gid) {
    for (int u = gid; u < Dsz * Dsz; u += NBLK * NTHR) {
        const int dd = u >> 9, k = u & 511;
        const float* pu = dU0 + (size_t)k * ND + dd;
        float a0 = pu[0], a1 = pu[Dsz], a2 = pu[2*Dsz], a3 = pu[3*Dsz];
        const float* dwr = dw + k * Fsz;
        for (int j = 0; j < Fsz; ++j) {
            const float wv = dwr[j];
            const float* dr = dW0 + (size_t)j * ND + dd;
            a0 += wv * dr[0]; a1 += wv * dr[Dsz];
            a2 += wv * dr[2*Dsz]; a3 += wv * dr[3*Dsz];
        }
        ((float4*)dst)[u] = make_float4(a0, a1, a2, a3);
    }
}

template<bool PACKED>
__global__ void __launch_bounds__(NTHR, 1)
lstm_ae_kernel(const float* enc_in, const float* dec_in,
               const float* eW0, const float* eU0, const float* eb0,
               const float* eW1, const float* eU1, const float* eb1,
               const float* dW0, const float* dU0, const float* db0,
               const float* dW1, const float* dU1, const float* db1,
               const float* dw, const float* db_, float* out, float* ws)
{
    __shared__ float XL[BPG * XSTR_MAX];
    __shared__ float RED[4096];
    __shared__ float ORED[1024];

    unsigned* slots = (unsigned*)ws;
    float* H[2] = { ws + OFF_H0, ws + OFF_H1 };
    float* C[2] = { ws + OFF_C0, ws + OFF_C1 };
    float* HM = ws + OFF_HM;
    float* CM = ws + OFF_CM;

    const int grp = blockIdx.x & 7;
    const int mem = blockIdx.x >> 3;
    const int gid = blockIdx.x * NTHR + threadIdx.x;
    unsigned ep = 0;

    const float *pEW0, *pEU0, *pWSUM, *pWDECA, *pDW0, *pDU0, *pDW1, *pDU1, *pBF, *pDWX;

    if (PACKED) {
        pack_gate(ws + OFF_P_EW0, eW0, Fsz, 7, gid);
        pack_gate(ws + OFF_P_EU0, eU0, Dsz, 9, gid);
        pack_wsum(ws + OFF_P_WSUM, eW1, eU1, gid);
        pack_wdeca_p(ws + OFF_P_WDECA, dU0, dW0, dw, gid);
        pack_gate(ws + OFF_P_DW0, dW0, Fsz, 7, gid);
        pack_gate(ws + OFF_P_DU0, dU0, Dsz, 9, gid);
        pack_gate(ws + OFF_P_DW1, dW1, Dsz, 9, gid);
        pack_gate(ws + OFF_P_DU1, dU1, Dsz, 9, gid);
        if (gid < ND) {
            float acc = db0[gid];
            for (int j = 0; j < Fsz; ++j) acc += db_[j] * dW0[(size_t)j * ND + gid];
            (ws + OFF_P_BF)[gid] = acc;
        }
        if (gid < Dsz * Fsz) {
            const int f = gid >> 9, k = gid & 511;
            (ws + OFF_P_DWT)[(size_t)f * Dsz + k] = dw[(size_t)k * Fsz + f];
        }
        pEW0 = ws + OFF_P_EW0; pEU0 = ws + OFF_P_EU0; pWSUM = ws + OFF_P_WSUM;
        pWDECA = ws + OFF_P_WDECA; pDW0 = ws + OFF_P_DW0; pDU0 = ws + OFF_P_DU0;
        pDW1 = ws + OFF_P_DW1; pDU1 = ws + OFF_P_DU1; pBF = ws + OFF_P_BF;
        pDWX = ws + OFF_P_DWT;
    } else {
        for (int i = gid; i < Dsz * ND; i += NBLK * NTHR)
            (ws + OFF_S_WSUM)[i] = eW1[i] + eU1[i];
        for (int u = gid; u < Dsz * ND; u += NBLK * NTHR) {
            const int k = u >> 11, col = u & (ND - 1);
            float acc = dU0[u];
            const float* dwr = dw + k * Fsz;
            for (int j = 0; j < Fsz; ++j) acc += dwr[j] * dW0[(size_t)j * ND + col];
            (ws + OFF_S_WDECA)[u] = acc;
        }
        if (gid < ND) {
            float acc = db0[gid];
            for (int j = 0; j < Fsz; ++j) acc += db_[j] * dW0[(size_t)j * ND + gid];
            (ws + OFF_S_BF)[gid] = acc;
        }
        pEW0 = eW0; pEU0 = eU0; pWSUM = ws + OFF_S_WSUM; pWDECA = ws + OFF_S_WDECA;
        pDW0 = dW0; pDU0 = dU0; pDW1 = dW1; pDU1 = dU1; pBF = ws + OFF_S_BF;
        pDWX = dw;
    }
    gbar_all(slots, grp, mem, ++ep);

    int cur = 0;

    for (int t = 0; t < Tsz; ++t) {
        cell_phase<PACKED>(XL, RED, ORED, grp, mem,
                           enc_in + (size_t)t * Fsz, Tsz * Fsz, Fsz, 5, pEW0,
                           H[cur], pEU0, eb0, C[cur], HM, CM,
                           nullptr, nullptr, nullptr, 0);
        gbar_group(slots, grp, mem, ++ep);
        cell_phase<PACKED>(XL, RED, ORED, grp, mem,
                           HM, Dsz, Dsz, 7, pWSUM,
                           nullptr, nullptr, eb1, CM, H[cur ^ 1], C[cur ^ 1],
                           nullptr, nullptr, nullptr, 0);
        gbar_group(slots, grp, mem, ++ep);
        cur ^= 1;
    }

    cell_phase<PACKED>(XL, RED, ORED, grp, mem,
                       dec_in, Tsz * Fsz, Fsz, 5, pDW0,
                       H[cur], pDU0, db0, C[cur], HM, nullptr,
                       nullptr, nullptr, nullptr, 0);
    gbar_group(slots, grp, mem, ++ep);
    cell_phase<PACKED>(XL, RED, ORED, grp, mem,
                       HM, Dsz, Dsz, 7, pDW1,
                       H[cur], pDU1, db1, C[cur], H[cur ^ 1], C[cur ^ 1],
                       nullptr, nullptr, nullptr, 0);
    gbar_group(slots, grp, mem, ++ep);
    cur ^= 1;

    for (int t = 1; t < Tsz; ++t) {
        cell_phase<PACKED>(XL, RED, ORED, grp, mem,
                           H[cur], Dsz, Dsz, 7, pWDECA,
                           nullptr, nullptr, pBF, C[cur], HM, nullptr,
                           pDWX, db_, out, Tsz - t);
        gbar_group(slots, grp, mem, ++ep);
        cell_phase<PACKED>(XL, RED, ORED, grp, mem,
                           HM, Dsz, Dsz, 7, pDW1,
                           H[cur], pDU1, db1, C[cur], H[cur ^ 1], C[cur ^ 1],
                           nullptr, nullptr, nullptr, 0);
        gbar_group(slots, grp, mem, ++ep);
        cur ^= 1;
    }

    out_only<PACKED>(XL, ORED, grp, mem, H[cur], pDWX, db_, out, 0);
}

extern "C" void kernel_launch(void* const* d_in, const int* in_sizes, int n_in,
                              void* d_out, int out_size, void* d_ws, size_t ws_size,
                              hipStream_t stream) {
    (void)in_sizes; (void)n_in; (void)out_size;
    const float* enc_in = (const float*)d_in[0];
    const float* dec_in = (const float*)d_in[1];
    const float* eW0 = (const float*)d_in[2];
    const float* eU0 = (const float*)d_in[3];
    const float* eb0 = (const float*)d_in[4];
    const float* eW1 = (const float*)d_in[5];
    const float* eU1 = (const float*)d_in[6];
    const float* eb1 = (const float*)d_in[7];
    const float* dW0 = (const float*)d_in[8];
    const float* dU0 = (const float*)d_in[9];
    const float* db0 = (const float*)d_in[10];
    const float* dW1 = (const float*)d_in[11];
    const float* dU1 = (const float*)d_in[12];
    const float* db1 = (const float*)d_in[13];
    const float* dw  = (const float*)d_in[14];
    const float* db_ = (const float*)d_in[15];
    float* out = (float*)d_out;
    float* ws = (float*)d_ws;

    hipMemsetAsync(d_ws, 0, (size_t)(OFF_H0 + 2 * Bsz * Dsz) * sizeof(float), stream);

    const bool packed = ws_size >= (size_t)WS_PACKED_FLOATS * sizeof(float);
    if (packed)
        lstm_ae_kernel<true><<<NBLK, NTHR, 0, stream>>>(
            enc_in, dec_in, eW0, eU0, eb0, eW1, eU1, eb1,
            dW0, dU0, db0, dW1, dU1, db1, dw, db_, out, ws);
    else
        lstm_ae_kernel<false><<<NBLK, NTHR, 0, stream>>>(
            enc_in, dec_in, eW0, eU0, eb0, eW1, eU1, eb1,
            dW0, dU0, db0, dW1, dU1, db1, dw, db_, out, ws);
}

// Round 5
// 16267.451 us; speedup vs baseline: 3.7460x; 3.0299x over previous
//
#include <hip/hip_runtime.h>

// LSTM autoencoder v5: v4 structure + corrected carry wiring.
//   Encoder step t: L0 cprev = c_car (prev step L1's c);  L0 outputs c1 (reg)
//                   L1 cprev = c1 (this step L0's c);     c_car = L1's c2
//   Decoder step t: BOTH layers cprev = c_car (old carry); L0's c discarded;
//                   c_car = L1's c2.   (matches jax scan semantics exactly)
// d-slice partitioning: grp=blockIdx&7 (XCD) owns dcols grp*64..+63 of every
// matrix -> per-XCD weight slice stays L2-resident across all 513 phases.
// Steady-loop barriers: release-store arrive + relaxed poll (NO acquire, NO
// threadfence -> no L2 invalidate). h state via relaxed agent-scope (sc1,
// L2-bypassing) atomic ld/st. c state entirely in registers.

#define Bsz 128
#define Tsz 128
#define Fsz 128
#define Dsz 512
#define ND  2048
#define NBLK 256
#define NTHR 1024
#define BPG 16

// ---- ws layout (float offsets) ----
#define OFF_H0   1024
#define OFF_H1   (OFF_H0 + Bsz*Dsz)
#define OFF_HM   (OFF_H1 + Bsz*Dsz)
#define OFF_WEND (OFF_HM + Bsz*Dsz)
// full-packed mode (gate-interleaved float4: Wp4[dcol*K + k] = {i,f,g,o})
#define OFF_P_EW0   OFF_WEND
#define OFF_P_EU0   (OFF_P_EW0 + Fsz*ND)
#define OFF_P_WSUM  (OFF_P_EU0 + Dsz*ND)
#define OFF_P_WDECA (OFF_P_WSUM + Dsz*ND)
#define OFF_P_DW0   (OFF_P_WDECA + Dsz*ND)
#define OFF_P_DU0   (OFF_P_DW0 + Fsz*ND)
#define OFF_P_DW1   (OFF_P_DU0 + Dsz*ND)
#define OFF_P_DU1   (OFF_P_DW1 + Dsz*ND)
#define OFF_P_BF    (OFF_P_DU1 + Dsz*ND)
#define OFF_P_DWT   (OFF_P_BF + ND)
#define WS_PACKED_FLOATS (OFF_P_DWT + Dsz*Fsz)
// fallback mode: only the must-materialize folded matrices (~9.45 MB total)
#define OFF_F_WSUM  OFF_WEND
#define OFF_F_WDECA (OFF_F_WSUM + Dsz*ND)
#define OFF_F_BF    (OFF_F_WDECA + Dsz*ND)
#define OFF_F_DWT   (OFF_F_BF + ND)
#define WS_FALLBACK_FLOATS (OFF_F_DWT + Dsz*Fsz)

__device__ __forceinline__ float sigf(float x) {
    return 1.0f / (1.0f + __expf(-x));
}

// relaxed agent-scope (L2-bypassing) scalar ld/st for h state
__device__ __forceinline__ float ld_coh(const float* p) {
    return __hip_atomic_load((float*)p, __ATOMIC_RELAXED, __HIP_MEMORY_SCOPE_AGENT);
}
__device__ __forceinline__ void st_coh(float* p, float v) {
    __hip_atomic_store(p, v, __ATOMIC_RELAXED, __HIP_MEMORY_SCOPE_AGENT);
}

// ---- flat grid barrier: 256 slots; arrive=release store; poll=relaxed ----
template<bool FULLFENCE>
__device__ __forceinline__ void gbar(unsigned* slots, int blkid, unsigned ep) {
    __syncthreads();
    if (threadIdx.x == 0) {
        if (FULLFENCE) __threadfence();   // P0 only: flush packed weights
        __hip_atomic_store(&slots[blkid], ep, __ATOMIC_RELEASE,
                           __HIP_MEMORY_SCOPE_AGENT);
    }
    if (threadIdx.x < 64) {
        unsigned* s = slots + threadIdx.x * 4;
        for (;;) {
            unsigned v0 = __hip_atomic_load(&s[0], __ATOMIC_RELAXED, __HIP_MEMORY_SCOPE_AGENT);
            unsigned v1 = __hip_atomic_load(&s[1], __ATOMIC_RELAXED, __HIP_MEMORY_SCOPE_AGENT);
            unsigned v2 = __hip_atomic_load(&s[2], __ATOMIC_RELAXED, __HIP_MEMORY_SCOPE_AGENT);
            unsigned m = (v0 < v1 ? v0 : v1);
            unsigned v3 = __hip_atomic_load(&s[3], __ATOMIC_RELAXED, __HIP_MEMORY_SCOPE_AGENT);
            m = (m < v2 ? m : v2); m = (m < v3 ? m : v3);
            if (__all(m >= ep)) break;
            __builtin_amdgcn_s_sleep(1);
        }
        if (FULLFENCE && threadIdx.x == 0) __threadfence();
    }
    __syncthreads();
}

// ---- staging into LDS (rows = this block's 16 samples) ----
__device__ __forceinline__ void stage_vec(float* XL, int xstr, int dstoff,
        const float* src, int row0, int ld, int klen, int c4shift) {
    const int q = klen >> 2;
    const int n4 = q * BPG;
    for (int i = threadIdx.x; i < n4; i += NTHR) {
        const int row = i >> c4shift;
        const int c4 = i & (q - 1);
        float4 v = *(const float4*)(src + (size_t)(row0 + row) * ld + (c4 << 2));
        *(float4*)(XL + row * xstr + dstoff + (c4 << 2)) = v;
    }
}
__device__ __forceinline__ void stage_coh(float* XL, int xstr, int dstoff,
        const float* src, int row0) {   // klen = Dsz (h buffers)
    const int n = Dsz * BPG;
    for (int i = threadIdx.x; i < n; i += NTHR) {
        const int row = i >> 9;
        const int col = i & (Dsz - 1);
        XL[row * xstr + dstoff + col] = ld_coh(src + (size_t)(row0 + row) * Dsz + col);
    }
}

// ---- gate accumulation ----
__device__ __forceinline__ void acc_seg(float4& z, const float* xp,
                                        const float4* wp, int ksub) {
    #pragma unroll 4
    for (int j = 0; j < ksub; j += 4) {
        float4 x4 = *(const float4*)(xp + j);
        float4 w0 = wp[j], w1 = wp[j + 1], w2 = wp[j + 2], w3 = wp[j + 3];
        z.x += x4.x*w0.x + x4.y*w1.x + x4.z*w2.x + x4.w*w3.x;
        z.y += x4.x*w0.y + x4.y*w1.y + x4.z*w2.y + x4.w*w3.y;
        z.z += x4.x*w0.z + x4.y*w1.z + x4.z*w2.z + x4.w*w3.z;
        z.w += x4.x*w0.w + x4.y*w1.w + x4.z*w2.w + x4.w*w3.w;
    }
}
__device__ __forceinline__ void acc_segS(float4& z, const float* xp,
                                         const float* W, int kbase, int ksub, int dcol) {
    for (int j = 0; j < ksub; ++j) {
        const float x = xp[j];
        const float* wr = W + (size_t)(kbase + j) * ND + dcol;
        z.x += x * wr[0];
        z.y += x * wr[Dsz];
        z.z += x * wr[2 * Dsz];
        z.w += x * wr[3 * Dsz];
    }
}

template<bool PACKED>
__device__ __forceinline__ float4 gates2(const float* XL, int xstr, int b, int kc,
                                         int dcol, int K0, const void* W0,
                                         const void* W1) {
    float4 z = make_float4(0.f, 0.f, 0.f, 0.f);
    const float* xrow = XL + b * xstr;
    {
        const int ksub = K0 >> 2;
        if (PACKED)
            acc_seg(z, xrow + kc * ksub,
                    (const float4*)W0 + (size_t)dcol * K0 + kc * ksub, ksub);
        else
            acc_segS(z, xrow + kc * ksub, (const float*)W0, kc * ksub, ksub, dcol);
    }
    if (W1) {
        const int ksub = Dsz >> 2;
        if (PACKED)
            acc_seg(z, xrow + K0 + kc * ksub,
                    (const float4*)W1 + (size_t)dcol * Dsz + kc * ksub, ksub);
        else
            acc_segS(z, xrow + K0 + kc * ksub, (const float*)W1, kc * ksub, ksub, dcol);
    }
    z.x += __shfl_xor(z.x, 16); z.x += __shfl_xor(z.x, 32);
    z.y += __shfl_xor(z.y, 16); z.y += __shfl_xor(z.y, 32);
    z.z += __shfl_xor(z.z, 16); z.z += __shfl_xor(z.z, 32);
    z.w += __shfl_xor(z.w, 16); z.w += __shfl_xor(z.w, 32);
    return z;
}

__device__ __forceinline__ float lstm_fin(float4 z, const float* bias, int dcol,
                                          float cprev, float& c2out) {
    float gi = sigf(z.x + bias[dcol]);
    float gf = sigf(z.y + bias[Dsz + dcol]);
    float gg = fmaxf(z.z + bias[2 * Dsz + dcol], 0.f);
    float go = sigf(z.w + bias[3 * Dsz + dcol]);
    float c2 = gf * cprev + gi * gg;
    c2out = c2;
    return go * fmaxf(c2, 0.f);
}

// ---- fused dense-row partial: out_row = x(@XL, K=512) @ dwT (packed [f][k]) ----
__device__ __forceinline__ void out_part(const float* XL, int xstr, float* ORED,
                                         int b, int kc, int w, int fcol,
                                         const float* dwT) {
    const int q = w >> 2;
    const float* xp = XL + b * xstr + q * 128 + kc * 32;
    const float* wt = dwT + (size_t)fcol * Dsz + q * 128 + kc * 32;
    float acc = 0.f;
    #pragma unroll
    for (int j = 0; j < 32; j += 4) {
        float4 x4 = *(const float4*)(xp + j);
        float4 w4 = *(const float4*)(wt + j);
        acc += x4.x * w4.x + x4.y * w4.y + x4.z * w4.z + x4.w * w4.w;
    }
    acc += __shfl_xor(acc, 16); acc += __shfl_xor(acc, 32);
    if ((threadIdx.x & 63) < 16) ORED[b * 16 + (w & 3) * 4 + q] = acc;
}

// ---- P0 packing ----
__device__ void pack_gate(float* dst, const float* src, int K, int kshift, int gid) {
    const int total = K * Dsz;
    for (int u = gid; u < total; u += NBLK * NTHR) {
        const int dd = u >> kshift;
        const int k = u & (K - 1);
        const float* sp = src + (size_t)k * ND + dd;
        ((float4*)dst)[u] = make_float4(sp[0], sp[Dsz], sp[2 * Dsz], sp[3 * Dsz]);
    }
}
__device__ void pack_wsum(float* dst, const float* a, const float* bsrc, int gid) {
    for (int u = gid; u < Dsz * Dsz; u += NBLK * NTHR) {
        const int dd = u >> 9, k = u & 511;
        const float* pa = a + (size_t)k * ND + dd;
        const float* pb = bsrc + (size_t)k * ND + dd;
        ((float4*)dst)[u] = make_float4(pa[0] + pb[0], pa[Dsz] + pb[Dsz],
                                        pa[2*Dsz] + pb[2*Dsz], pa[3*Dsz] + pb[3*Dsz]);
    }
}
__device__ void pack_wdeca_p(float* dst, const float* dU0, const float* dW0,
                             const float* dw, int gid) {
    for (int u = gid; u < Dsz * Dsz; u += NBLK * NTHR) {
        const int dd = u >> 9, k = u & 511;
        const float* pu = dU0 + (size_t)k * ND + dd;
        float a0 = pu[0], a1 = pu[Dsz], a2 = pu[2*Dsz], a3 = pu[3*Dsz];
        const float* dwr = dw + k * Fsz;
        for (int j = 0; j < Fsz; ++j) {
            const float wv = dwr[j];
            const float* dr = dW0 + (size_t)j * ND + dd;
            a0 += wv * dr[0]; a1 += wv * dr[Dsz];
            a2 += wv * dr[2*Dsz]; a3 += wv * dr[3*Dsz];
        }
        ((float4*)dst)[u] = make_float4(a0, a1, a2, a3);
    }
}

template<bool PACKED>
__global__ void __launch_bounds__(NTHR, 1)
lstm_ae_kernel(const float* enc_in, const float* dec_in,
               const float* eW0, const float* eU0, const float* eb0,
               const float* eW1, const float* eU1, const float* eb1,
               const float* dW0, const float* dU0, const float* db0,
               const float* dW1, const float* dU1, const float* db1,
               const float* dw, const float* db_, float* out, float* ws)
{
    __shared__ float XL[BPG * 1028];
    __shared__ float ORED[256];

    unsigned* slots = (unsigned*)ws;
    float* H[2] = { ws + OFF_H0, ws + OFF_H1 };
    float* HM = ws + OFF_HM;

    const int blkid = blockIdx.x;
    const int grp  = blkid & 7;
    const int mem  = blkid >> 3;
    const int sgrp = mem & 7;
    const int dslc = mem >> 3;
    const int tid  = threadIdx.x;
    const int w    = tid >> 6;
    const int lane = tid & 63;
    const int b    = lane & 15;
    const int kc   = lane >> 4;
    const int dcol = grp * 64 + dslc * 16 + w;
    const int bgl  = sgrp * 16 + b;
    const int row0 = sgrp * 16;
    const int fcol = grp * 16 + dslc * 4 + (w & 3);
    const int gid  = blkid * NTHR + tid;
    unsigned ep = 0;

    const float *pEW0, *pEU0, *pWSUM, *pWDECA, *pDW0, *pDU0, *pDW1, *pDU1, *pBF, *pDWT;

    // ---- P0: fold + pack (plain stores; flushed by the full-fence barrier) ----
    if (PACKED) {
        pack_gate(ws + OFF_P_EW0, eW0, Fsz, 7, gid);
        pack_gate(ws + OFF_P_EU0, eU0, Dsz, 9, gid);
        pack_wsum(ws + OFF_P_WSUM, eW1, eU1, gid);
        pack_wdeca_p(ws + OFF_P_WDECA, dU0, dW0, dw, gid);
        pack_gate(ws + OFF_P_DW0, dW0, Fsz, 7, gid);
        pack_gate(ws + OFF_P_DU0, dU0, Dsz, 9, gid);
        pack_gate(ws + OFF_P_DW1, dW1, Dsz, 9, gid);
        pack_gate(ws + OFF_P_DU1, dU1, Dsz, 9, gid);
        if (gid < ND) {
            float acc = db0[gid];
            for (int j = 0; j < Fsz; ++j) acc += db_[j] * dW0[(size_t)j * ND + gid];
            (ws + OFF_P_BF)[gid] = acc;
        }
        if (gid < Dsz * Fsz) {   // dwT[f][k]
            const int f = gid >> 9, k = gid & 511;
            (ws + OFF_P_DWT)[(size_t)f * Dsz + k] = dw[(size_t)k * Fsz + f];
        }
        pEW0 = ws + OFF_P_EW0; pEU0 = ws + OFF_P_EU0; pWSUM = ws + OFF_P_WSUM;
        pWDECA = ws + OFF_P_WDECA; pDW0 = ws + OFF_P_DW0; pDU0 = ws + OFF_P_DU0;
        pDW1 = ws + OFF_P_DW1; pDU1 = ws + OFF_P_DU1; pBF = ws + OFF_P_BF;
        pDWT = ws + OFF_P_DWT;
    } else {
        // fallback: materialize only folded matrices (~9.45 MB); strided reads
        // for the six raw weight matrices.
        pack_wsum(ws + OFF_F_WSUM, eW1, eU1, gid);
        pack_wdeca_p(ws + OFF_F_WDECA, dU0, dW0, dw, gid);
        if (gid < ND) {
            float acc = db0[gid];
            for (int j = 0; j < Fsz; ++j) acc += db_[j] * dW0[(size_t)j * ND + gid];
            (ws + OFF_F_BF)[gid] = acc;
        }
        if (gid < Dsz * Fsz) {
            const int f = gid >> 9, k = gid & 511;
            (ws + OFF_F_DWT)[(size_t)f * Dsz + k] = dw[(size_t)k * Fsz + f];
        }
        pEW0 = eW0; pEU0 = eU0; pWSUM = ws + OFF_F_WSUM;
        pWDECA = ws + OFF_F_WDECA; pDW0 = dW0; pDU0 = dU0;
        pDW1 = dW1; pDU1 = dU1; pBF = ws + OFF_F_BF;
        pDWT = ws + OFF_F_DWT;
    }
    gbar<true>(slots, blkid, ++ep);

    int cur = 0;
    float c_car = 0.f;   // the scan's single c carry (valid on lanes<16)

    // ---- encoder ----
    for (int t = 0; t < Tsz; ++t) {
        // L0: z = x_t@eW0 + h@eU0 ; cprev = c_car (prev step L1 c); c1 -> reg
        stage_vec(XL, 644, 0, enc_in + (size_t)t * Fsz, row0, Tsz * Fsz, 128, 5);
        stage_coh(XL, 644, 128, H[cur], row0);
        __syncthreads();
        float4 z = gates2<PACKED>(XL, 644, b, kc, dcol, 128, pEW0, pEU0);
        float c1 = 0.f;
        if (lane < 16) {
            float h2 = lstm_fin(z, eb0, dcol, c_car, c1);
            st_coh(&HM[(size_t)bgl * Dsz + dcol], h2);
        }
        gbar<false>(slots, blkid, ++ep);
        // L1: z = h1@(eW1+eU1) ; cprev = c1 (this step L0 c); c_car = c2
        stage_coh(XL, 516, 0, HM, row0);
        __syncthreads();
        z = gates2<true>(XL, 516, b, kc, dcol, Dsz, pWSUM, nullptr);
        if (lane < 16) {
            float c2;
            float h2 = lstm_fin(z, eb1, dcol, c1, c2);
            c_car = c2;
            st_coh(&H[cur ^ 1][(size_t)bgl * Dsz + dcol], h2);
        }
        gbar<false>(slots, blkid, ++ep);
        cur ^= 1;
    }

    // ---- decoder t=0 (both layers consume the OLD carry) ----
    stage_vec(XL, 644, 0, dec_in, row0, Tsz * Fsz, 128, 5);
    stage_coh(XL, 644, 128, H[cur], row0);
    __syncthreads();
    {
        float4 z = gates2<PACKED>(XL, 644, b, kc, dcol, 128, pDW0, pDU0);
        if (lane < 16) {
            float cd;
            float h2 = lstm_fin(z, db0, dcol, c_car, cd);  // L0 c discarded
            st_coh(&HM[(size_t)bgl * Dsz + dcol], h2);
        }
    }
    gbar<false>(slots, blkid, ++ep);
    stage_coh(XL, 1028, 0, HM, row0);
    stage_coh(XL, 1028, 512, H[cur], row0);
    __syncthreads();
    {
        float4 z = gates2<PACKED>(XL, 1028, b, kc, dcol, 512, pDW1, pDU1);
        if (lane < 16) {
            float c2;
            float h2 = lstm_fin(z, db1, dcol, c_car, c2);
            c_car = c2;
            st_coh(&H[cur ^ 1][(size_t)bgl * Dsz + dcol], h2);
        }
    }
    gbar<false>(slots, blkid, ++ep);
    cur ^= 1;

    // ---- decoder t=1..127 (folded input; emit out_{t-1} at row T-t) ----
    for (int t = 1; t < Tsz; ++t) {
        const int tt = Tsz - t;
        // L0 folded: z = h@WdecA + bfold ; fused out_{t-1} = h@dense_W + db
        stage_coh(XL, 516, 0, H[cur], row0);
        __syncthreads();
        float4 z = gates2<true>(XL, 516, b, kc, dcol, Dsz, pWDECA, nullptr);
        out_part(XL, 516, ORED, b, kc, w, fcol, pDWT);
        if (lane < 16) {
            float cd;
            float h2 = lstm_fin(z, pBF, dcol, c_car, cd);  // L0 c discarded
            st_coh(&HM[(size_t)bgl * Dsz + dcol], h2);
        }
        __syncthreads();
        if (tid < 64) {
            const int bb = tid >> 2, ff = tid & 3;
            const int fc = grp * 16 + dslc * 4 + ff;
            const float* r = ORED + bb * 16 + ff * 4;
            float s = r[0] + r[1] + r[2] + r[3] + db_[fc];
            out[((size_t)(sgrp * 16 + bb) * Tsz + tt) * Fsz + fc] = s;
        }
        gbar<false>(slots, blkid, ++ep);
        // L1: z = hA@dW1 + h@dU1 ; cprev = old c_car; update carry
        stage_coh(XL, 1028, 0, HM, row0);
        stage_coh(XL, 1028, 512, H[cur], row0);
        __syncthreads();
        {
            float4 z1 = gates2<PACKED>(XL, 1028, b, kc, dcol, 512, pDW1, pDU1);
            if (lane < 16) {
                float c2;
                float h2 = lstm_fin(z1, db1, dcol, c_car, c2);
                c_car = c2;
                st_coh(&H[cur ^ 1][(size_t)bgl * Dsz + dcol], h2);
            }
        }
        gbar<false>(slots, blkid, ++ep);
        cur ^= 1;
    }

    // ---- final: out_127 -> row 0 ----
    stage_coh(XL, 516, 0, H[cur], row0);
    __syncthreads();
    out_part(XL, 516, ORED, b, kc, w, fcol, pDWT);
    __syncthreads();
    if (tid < 64) {
        const int bb = tid >> 2, ff = tid & 3;
        const int fc = grp * 16 + dslc * 4 + ff;
        const float* r = ORED + bb * 16 + ff * 4;
        float s = r[0] + r[1] + r[2] + r[3] + db_[fc];
        out[((size_t)(sgrp * 16 + bb) * Tsz + 0) * Fsz + fc] = s;
    }
}

extern "C" void kernel_launch(void* const* d_in, const int* in_sizes, int n_in,
                              void* d_out, int out_size, void* d_ws, size_t ws_size,
                              hipStream_t stream) {
    (void)in_sizes; (void)n_in; (void)out_size;
    const float* enc_in = (const float*)d_in[0];
    const float* dec_in = (const float*)d_in[1];
    const float* eW0 = (const float*)d_in[2];
    const float* eU0 = (const float*)d_in[3];
    const float* eb0 = (const float*)d_in[4];
    const float* eW1 = (const float*)d_in[5];
    const float* eU1 = (const float*)d_in[6];
    const float* eb1 = (const float*)d_in[7];
    const float* dW0 = (const float*)d_in[8];
    const float* dU0 = (const float*)d_in[9];
    const float* db0 = (const float*)d_in[10];
    const float* dW1 = (const float*)d_in[11];
    const float* dU1 = (const float*)d_in[12];
    const float* db1 = (const float*)d_in[13];
    const float* dw  = (const float*)d_in[14];
    const float* db_ = (const float*)d_in[15];
    float* out = (float*)d_out;
    float* ws = (float*)d_ws;

    // zero: barrier slots + H0 (initial h)
    hipMemsetAsync(d_ws, 0, (size_t)(OFF_H0 + Bsz * Dsz) * sizeof(float), stream);

    const bool packed = ws_size >= (size_t)WS_PACKED_FLOATS * sizeof(float);
    if (packed)
        lstm_ae_kernel<true><<<NBLK, NTHR, 0, stream>>>(
            enc_in, dec_in, eW0, eU0, eb0, eW1, eU1, eb1,
            dW0, dU0, db0, dW1, dU1, db1, dw, db_, out, ws);
    else
        lstm_ae_kernel<false><<<NBLK, NTHR, 0, stream>>>(
            enc_in, dec_in, eW0, eU0, eb0, eW1, eU1, eb1,
            dW0, dU0, db0, dW1, dU1, db1, dw, db_, out, ws);
}

// Round 6
// 13244.019 us; speedup vs baseline: 4.6012x; 1.2283x over previous
//
#include <hip/hip_runtime.h>

// LSTM autoencoder v6: v5 + per-sample-group barriers (32-block domains),
// transposed h buffers (coalesced coherent stores), split arrive/wait with
// static-x prefetch + partial-compute overlap, dec-L1 LDS h reuse.
// d-slice partitioning unchanged: grp=blkid&7 (XCD) owns dcols grp*64..+63 ->
// weights stay L2-resident (R5: FETCH 24GB->0.89GB). No acquire/fence in the
// steady loop. h via relaxed agent-scope atomics; c in registers.

#define Bsz 128
#define Tsz 128
#define Fsz 128
#define Dsz 512
#define ND  2048
#define NBLK 256
#define NTHR 1024

// ---- ws layout (float offsets) ----
// [0,256) full-grid slots (uint); [256,768) group slots: group s at 256+s*64
#define OFF_HT0  1024
#define OFF_HT1  (OFF_HT0 + Dsz*Bsz)
#define OFF_HMT  (OFF_HT1 + Dsz*Bsz)
#define OFF_WEND (OFF_HMT + Dsz*Bsz)
// packed weights (gate-interleaved float4: Wp4[dcol*K + k] = {i,f,g,o})
#define OFF_P_EW0   OFF_WEND
#define OFF_P_EU0   (OFF_P_EW0 + Fsz*ND)
#define OFF_P_WSUM  (OFF_P_EU0 + Dsz*ND)
#define OFF_P_WDECA (OFF_P_WSUM + Dsz*ND)
#define OFF_P_DW0   (OFF_P_WDECA + Dsz*ND)
#define OFF_P_DU0   (OFF_P_DW0 + Fsz*ND)
#define OFF_P_DW1   (OFF_P_DU0 + Dsz*ND)
#define OFF_P_DU1   (OFF_P_DW1 + Dsz*ND)
#define OFF_P_BF    (OFF_P_DU1 + Dsz*ND)
#define OFF_P_DWT   (OFF_P_BF + ND)
#define WS_PACKED_FLOATS (OFF_P_DWT + Dsz*Fsz)
// fallback: only folded matrices packed; raw mats strided
#define OFF_F_WSUM  OFF_WEND
#define OFF_F_WDECA (OFF_F_WSUM + Dsz*ND)
#define OFF_F_BF    (OFF_F_WDECA + Dsz*ND)
#define OFF_F_DWT   (OFF_F_BF + ND)
#define WS_FALLBACK_FLOATS (OFF_F_DWT + Dsz*Fsz)

__device__ __forceinline__ float sigf(float x) {
    return 1.0f / (1.0f + __expf(-x));
}

__device__ __forceinline__ float ld_coh(const float* p) {
    return __hip_atomic_load((float*)p, __ATOMIC_RELAXED, __HIP_MEMORY_SCOPE_AGENT);
}
__device__ __forceinline__ void st_coh(float* p, float v) {
    __hip_atomic_store(p, v, __ATOMIC_RELAXED, __HIP_MEMORY_SCOPE_AGENT);
}

// ---- split group barrier (32 members) ----
__device__ __forceinline__ void arrive(unsigned* slot, unsigned ep) {
    __syncthreads();   // all waves' compute + coherent stores drained (vmcnt0)
    if (threadIdx.x == 0)
        __hip_atomic_store(slot, ep, __ATOMIC_RELEASE, __HIP_MEMORY_SCOPE_AGENT);
}
__device__ __forceinline__ void wait_grp(unsigned* gslots, unsigned ep) {
    if (threadIdx.x < 64) {
        for (;;) {
            unsigned v = (threadIdx.x < 32)
                ? __hip_atomic_load(&gslots[threadIdx.x], __ATOMIC_RELAXED,
                                    __HIP_MEMORY_SCOPE_AGENT)
                : ep;
            if (__all(v >= ep)) break;
            __builtin_amdgcn_s_sleep(1);
        }
    }
    __syncthreads();
}
// ---- full-grid barrier (P0 only) ----
__device__ __forceinline__ void gbar_all(unsigned* slots, int blkid, unsigned ep) {
    __syncthreads();
    if (threadIdx.x == 0) {
        __threadfence();
        __hip_atomic_store(&slots[blkid], ep, __ATOMIC_RELEASE,
                           __HIP_MEMORY_SCOPE_AGENT);
    }
    if (threadIdx.x < 64) {
        for (;;) {
            unsigned mn = ~0u;
            #pragma unroll
            for (int q = 0; q < 4; ++q) {
                unsigned v = __hip_atomic_load(&slots[threadIdx.x * 4 + q],
                                               __ATOMIC_RELAXED, __HIP_MEMORY_SCOPE_AGENT);
                mn = min(mn, v);
            }
            if (__all(mn >= ep)) break;
            __builtin_amdgcn_s_sleep(1);
        }
        if (threadIdx.x == 0) __threadfence();
    }
    __syncthreads();
}

// ---- staging ----
__device__ __forceinline__ void stage_vec(float* XL, int xstr, int dstoff,
        const float* src, int row0, int ld, int klen, int c4shift) {
    const int q = klen >> 2;
    const int n4 = q * 16;
    for (int i = threadIdx.x; i < n4; i += NTHR) {
        const int row = i >> c4shift;
        const int c4 = i & (q - 1);
        float4 v = *(const float4*)(src + (size_t)(row0 + row) * ld + (c4 << 2));
        *(float4*)(XL + row * xstr + dstoff + (c4 << 2)) = v;
    }
}
// transposed h buffer HTsrc[dcol*Bsz + bgl] -> XL[b*xstr + dstoff + dcol]
__device__ __forceinline__ void stage_coh_T(float* XL, int xstr, int dstoff,
        const float* HTsrc, int row0) {
    for (int i = threadIdx.x; i < Dsz * 16; i += NTHR) {
        const int d = i >> 4;
        const int bb = i & 15;
        XL[bb * xstr + dstoff + d] = ld_coh(HTsrc + (size_t)d * Bsz + row0 + bb);
    }
}

// ---- gate accumulation ----
__device__ __forceinline__ void acc_seg(float4& z, const float* xp,
                                        const float4* wp, int ksub) {
    #pragma unroll 4
    for (int j = 0; j < ksub; j += 4) {
        float4 x4 = *(const float4*)(xp + j);
        float4 w0 = wp[j], w1 = wp[j + 1], w2 = wp[j + 2], w3 = wp[j + 3];
        z.x += x4.x*w0.x + x4.y*w1.x + x4.z*w2.x + x4.w*w3.x;
        z.y += x4.x*w0.y + x4.y*w1.y + x4.z*w2.y + x4.w*w3.y;
        z.z += x4.x*w0.z + x4.y*w1.z + x4.z*w2.z + x4.w*w3.z;
        z.w += x4.x*w0.w + x4.y*w1.w + x4.z*w2.w + x4.w*w3.w;
    }
}
__device__ __forceinline__ void acc_segS(float4& z, const float* xp,
                                         const float* W, int kbase, int ksub, int dcol) {
    for (int j = 0; j < ksub; ++j) {
        const float x = xp[j];
        const float* wr = W + (size_t)(kbase + j) * ND + dcol;
        z.x += x * wr[0];
        z.y += x * wr[Dsz];
        z.z += x * wr[2 * Dsz];
        z.w += x * wr[3 * Dsz];
    }
}
__device__ __forceinline__ void reduce4(float4& z) {
    z.x += __shfl_xor(z.x, 16); z.x += __shfl_xor(z.x, 32);
    z.y += __shfl_xor(z.y, 16); z.y += __shfl_xor(z.y, 32);
    z.z += __shfl_xor(z.z, 16); z.z += __shfl_xor(z.z, 32);
    z.w += __shfl_xor(z.w, 16); z.w += __shfl_xor(z.w, 32);
}

__device__ __forceinline__ float lstm_fin(float4 z, const float* bias, int dcol,
                                          float cprev, float& c2out) {
    float gi = sigf(z.x + bias[dcol]);
    float gf = sigf(z.y + bias[Dsz + dcol]);
    float gg = fmaxf(z.z + bias[2 * Dsz + dcol], 0.f);
    float go = sigf(z.w + bias[3 * Dsz + dcol]);
    float c2 = gf * cprev + gi * gg;
    c2out = c2;
    return go * fmaxf(c2, 0.f);
}

// ---- fused dense-row partial: h(@XL cols[0,512)) @ dwT[f][k] ----
__device__ __forceinline__ void out_part(const float* XL, int xstr, float* ORED,
                                         int b, int kc, int w, int fcol,
                                         const float* dwT) {
    const int q = w >> 2;
    const float* xp = XL + b * xstr + q * 128 + kc * 32;
    const float* wt = dwT + (size_t)fcol * Dsz + q * 128 + kc * 32;
    float acc = 0.f;
    #pragma unroll
    for (int j = 0; j < 32; j += 4) {
        float4 x4 = *(const float4*)(xp + j);
        float4 w4 = *(const float4*)(wt + j);
        acc += x4.x * w4.x + x4.y * w4.y + x4.z * w4.z + x4.w * w4.w;
    }
    acc += __shfl_xor(acc, 16); acc += __shfl_xor(acc, 32);
    if ((threadIdx.x & 63) < 16) ORED[b * 16 + (w & 3) * 4 + q] = acc;
}

// ---- P0 packing ----
__device__ void pack_gate(float* dst, const float* src, int K, int kshift, int gid) {
    const int total = K * Dsz;
    for (int u = gid; u < total; u += NBLK * NTHR) {
        const int dd = u >> kshift;
        const int k = u & (K - 1);
        const float* sp = src + (size_t)k * ND + dd;
        ((float4*)dst)[u] = make_float4(sp[0], sp[Dsz], sp[2 * Dsz], sp[3 * Dsz]);
    }
}
__device__ void pack_wsum(float* dst, const float* a, const float* bsrc, int gid) {
    for (int u = gid; u < Dsz * Dsz; u += NBLK * NTHR) {
        const int dd = u >> 9, k = u & 511;
        const float* pa = a + (size_t)k * ND + dd;
        const float* pb = bsrc + (size_t)k * ND + dd;
        ((float4*)dst)[u] = make_float4(pa[0] + pb[0], pa[Dsz] + pb[Dsz],
                                        pa[2*Dsz] + pb[2*Dsz], pa[3*Dsz] + pb[3*Dsz]);
    }
}
__device__ void pack_wdeca_p(float* dst, const float* dU0, const float* dW0,
                             const float* dw, int gid) {
    for (int u = gid; u < Dsz * Dsz; u += NBLK * NTHR) {
        const int dd = u >> 9, k = u & 511;
        const float* pu = dU0 + (size_t)k * ND + dd;
        float a0 = pu[0], a1 = pu[Dsz], a2 = pu[2*Dsz], a3 = pu[3*Dsz];
        const float* dwr = dw + k * Fsz;
        for (int j = 0; j < Fsz; ++j) {
            const float wv = dwr[j];
            const float* dr = dW0 + (size_t)j * ND + dd;
            a0 += wv * dr[0]; a1 += wv * dr[Dsz];
            a2 += wv * dr[2*Dsz]; a3 += wv * dr[3*Dsz];
        }
        ((float4*)dst)[u] = make_float4(a0, a1, a2, a3);
    }
}

template<bool PACKED>
__global__ void __launch_bounds__(NTHR, 1)
lstm_ae_kernel(const float* enc_in, const float* dec_in,
               const float* eW0, const float* eU0, const float* eb0,
               const float* eW1, const float* eU1, const float* eb1,
               const float* dW0, const float* dU0, const float* db0,
               const float* dW1, const float* dU1, const float* db1,
               const float* dw, const float* db_, float* out, float* ws)
{
    __shared__ float XL[16 * 1028];
    __shared__ float ORED[256];

    unsigned* fslots = (unsigned*)ws;                     // 256 full-grid
    float* HT[2] = { ws + OFF_HT0, ws + OFF_HT1 };        // [dcol][bgl]
    float* HMT = ws + OFF_HMT;

    const int blkid = blockIdx.x;
    const int grp  = blkid & 7;       // XCD / dcol-slice owner
    const int mem  = blkid >> 3;      // 0..31
    const int sgrp = mem & 7;         // sample group (barrier domain)
    const int dslc = mem >> 3;        // 0..3
    const int gm   = dslc * 8 + grp;  // member id within group (0..31)
    unsigned* gslots = (unsigned*)ws + 256 + sgrp * 64;

    const int tid  = threadIdx.x;
    const int w    = tid >> 6;
    const int lane = tid & 63;
    const int b    = lane & 15;
    const int kc   = lane >> 4;
    const int dcol = grp * 64 + dslc * 16 + w;
    const int bgl  = sgrp * 16 + b;
    const int row0 = sgrp * 16;
    const int fcol = grp * 16 + dslc * 4 + (w & 3);
    const int gid  = blkid * NTHR + tid;

    const float *pEW0, *pEU0, *pWSUM, *pWDECA, *pDW0, *pDU0, *pDW1, *pDU1, *pBF, *pDWT;

    // ---- P0 ----
    if (PACKED) {
        pack_gate(ws + OFF_P_EW0, eW0, Fsz, 7, gid);
        pack_gate(ws + OFF_P_EU0, eU0, Dsz, 9, gid);
        pack_wsum(ws + OFF_P_WSUM, eW1, eU1, gid);
        pack_wdeca_p(ws + OFF_P_WDECA, dU0, dW0, dw, gid);
        pack_gate(ws + OFF_P_DW0, dW0, Fsz, 7, gid);
        pack_gate(ws + OFF_P_DU0, dU0, Dsz, 9, gid);
        pack_gate(ws + OFF_P_DW1, dW1, Dsz, 9, gid);
        pack_gate(ws + OFF_P_DU1, dU1, Dsz, 9, gid);
        if (gid < ND) {
            float acc = db0[gid];
            for (int j = 0; j < Fsz; ++j) acc += db_[j] * dW0[(size_t)j * ND + gid];
            (ws + OFF_P_BF)[gid] = acc;
        }
        if (gid < Dsz * Fsz) {
            const int f = gid >> 9, k = gid & 511;
            (ws + OFF_P_DWT)[(size_t)f * Dsz + k] = dw[(size_t)k * Fsz + f];
        }
        pEW0 = ws + OFF_P_EW0; pEU0 = ws + OFF_P_EU0; pWSUM = ws + OFF_P_WSUM;
        pWDECA = ws + OFF_P_WDECA; pDW0 = ws + OFF_P_DW0; pDU0 = ws + OFF_P_DU0;
        pDW1 = ws + OFF_P_DW1; pDU1 = ws + OFF_P_DU1; pBF = ws + OFF_P_BF;
        pDWT = ws + OFF_P_DWT;
    } else {
        pack_wsum(ws + OFF_F_WSUM, eW1, eU1, gid);
        pack_wdeca_p(ws + OFF_F_WDECA, dU0, dW0, dw, gid);
        if (gid < ND) {
            float acc = db0[gid];
            for (int j = 0; j < Fsz; ++j) acc += db_[j] * dW0[(size_t)j * ND + gid];
            (ws + OFF_F_BF)[gid] = acc;
        }
        if (gid < Dsz * Fsz) {
            const int f = gid >> 9, k = gid & 511;
            (ws + OFF_F_DWT)[(size_t)f * Dsz + k] = dw[(size_t)k * Fsz + f];
        }
        pEW0 = eW0; pEU0 = eU0; pWSUM = ws + OFF_F_WSUM;
        pWDECA = ws + OFF_F_WDECA; pDW0 = dW0; pDU0 = dU0;
        pDW1 = dW1; pDU1 = dU1; pBF = ws + OFF_F_BF;
        pDWT = ws + OFF_F_DWT;
    }
    gbar_all(fslots, blkid, 1);

    unsigned ep = 0;       // group-barrier epoch (completed phases)
    int cur = 0;
    float c_car = 0.f;

    // ---- encoder ----
    for (int t = 0; t < Tsz; ++t) {
        // L0: prestage x_t + partial zx BEFORE waiting for h_{t-1}
        stage_vec(XL, 644, 0, enc_in + (size_t)t * Fsz, row0, Tsz * Fsz, 128, 5);
        __syncthreads();
        float4 z = make_float4(0.f, 0.f, 0.f, 0.f);
        if (PACKED) acc_seg(z, XL + b * 644 + kc * 32,
                            (const float4*)pEW0 + (size_t)dcol * 128 + kc * 32, 32);
        else        acc_segS(z, XL + b * 644 + kc * 32, pEW0, kc * 32, 32, dcol);
        wait_grp(gslots, ep);
        stage_coh_T(XL, 644, 128, HT[cur], row0);
        __syncthreads();
        if (PACKED) acc_seg(z, XL + b * 644 + 128 + kc * 128,
                            (const float4*)pEU0 + (size_t)dcol * 512 + kc * 128, 128);
        else        acc_segS(z, XL + b * 644 + 128 + kc * 128, pEU0, kc * 128, 128, dcol);
        reduce4(z);
        float c1 = 0.f;
        if (lane < 16) {
            float h2 = lstm_fin(z, eb0, dcol, c_car, c1);
            st_coh(&HMT[(size_t)dcol * Bsz + bgl], h2);
        }
        arrive(&gslots[gm], ++ep);
        // L1: h1@(eW1+eU1); cprev = c1
        wait_grp(gslots, ep);
        stage_coh_T(XL, 516, 0, HMT, row0);
        __syncthreads();
        z = make_float4(0.f, 0.f, 0.f, 0.f);
        acc_seg(z, XL + b * 516 + kc * 128,
                (const float4*)pWSUM + (size_t)dcol * 512 + kc * 128, 128);
        reduce4(z);
        if (lane < 16) {
            float c2;
            float h2 = lstm_fin(z, eb1, dcol, c1, c2);
            c_car = c2;
            st_coh(&HT[cur ^ 1][(size_t)dcol * Bsz + bgl], h2);
        }
        arrive(&gslots[gm], ++ep);
        cur ^= 1;
    }

    // ---- decoder t=0 (both layers consume OLD carry; L0 c discarded) ----
    stage_vec(XL, 644, 0, dec_in, row0, Tsz * Fsz, 128, 5);
    __syncthreads();
    {
        float4 z = make_float4(0.f, 0.f, 0.f, 0.f);
        if (PACKED) acc_seg(z, XL + b * 644 + kc * 32,
                            (const float4*)pDW0 + (size_t)dcol * 128 + kc * 32, 32);
        else        acc_segS(z, XL + b * 644 + kc * 32, pDW0, kc * 32, 32, dcol);
        wait_grp(gslots, ep);
        stage_coh_T(XL, 644, 128, HT[cur], row0);
        __syncthreads();
        if (PACKED) acc_seg(z, XL + b * 644 + 128 + kc * 128,
                            (const float4*)pDU0 + (size_t)dcol * 512 + kc * 128, 128);
        else        acc_segS(z, XL + b * 644 + 128 + kc * 128, pDU0, kc * 128, 128, dcol);
        reduce4(z);
        if (lane < 16) {
            float cd;
            float h2 = lstm_fin(z, db0, dcol, c_car, cd);
            st_coh(&HMT[(size_t)dcol * Bsz + bgl], h2);
        }
        arrive(&gslots[gm], ++ep);
    }
    // t=0 L1: stage h(old)->[0,512) and hA->[512,1024), xstr 1028
    wait_grp(gslots, ep);
    stage_coh_T(XL, 1028, 0, HT[cur], row0);
    stage_coh_T(XL, 1028, 512, HMT, row0);
    __syncthreads();
    {
        float4 z = make_float4(0.f, 0.f, 0.f, 0.f);
        if (PACKED) {
            acc_seg(z, XL + b * 1028 + kc * 128,
                    (const float4*)pDU1 + (size_t)dcol * 512 + kc * 128, 128);
            acc_seg(z, XL + b * 1028 + 512 + kc * 128,
                    (const float4*)pDW1 + (size_t)dcol * 512 + kc * 128, 128);
        } else {
            acc_segS(z, XL + b * 1028 + kc * 128, pDU1, kc * 128, 128, dcol);
            acc_segS(z, XL + b * 1028 + 512 + kc * 128, pDW1, kc * 128, 128, dcol);
        }
        reduce4(z);
        if (lane < 16) {
            float c2;
            float h2 = lstm_fin(z, db1, dcol, c_car, c2);
            c_car = c2;
            st_coh(&HT[cur ^ 1][(size_t)dcol * Bsz + bgl], h2);
        }
    }
    arrive(&gslots[gm], ++ep);
    cur ^= 1;

    // ---- decoder t=1..127 ----
    for (int t = 1; t < Tsz; ++t) {
        const int tt = Tsz - t;
        // L0 folded: h@WdecA + bfold ; fused out_{t-1} partials; h stays in LDS
        wait_grp(gslots, ep);
        stage_coh_T(XL, 1028, 0, HT[cur], row0);
        __syncthreads();
        {
            float4 z = make_float4(0.f, 0.f, 0.f, 0.f);
            acc_seg(z, XL + b * 1028 + kc * 128,
                    (const float4*)pWDECA + (size_t)dcol * 512 + kc * 128, 128);
            reduce4(z);
            out_part(XL, 1028, ORED, b, kc, w, fcol, pDWT);
            if (lane < 16) {
                float cd;
                float h2 = lstm_fin(z, pBF, dcol, c_car, cd);
                st_coh(&HMT[(size_t)dcol * Bsz + bgl], h2);
            }
        }
        arrive(&gslots[gm], ++ep);
        // out row emit off the critical path (ORED complete after arrive's sync)
        if (tid < 64) {
            const int bb = tid >> 2, ff = tid & 3;
            const int fc = grp * 16 + dslc * 4 + ff;
            const float* r = ORED + bb * 16 + ff * 4;
            float s = r[0] + r[1] + r[2] + r[3] + db_[fc];
            out[((size_t)(row0 + bb) * Tsz + tt) * Fsz + fc] = s;
        }
        // L1: hA@dW1 + h@dU1 ; h reused from LDS cols [0,512)
        wait_grp(gslots, ep);
        stage_coh_T(XL, 1028, 512, HMT, row0);
        __syncthreads();
        {
            float4 z = make_float4(0.f, 0.f, 0.f, 0.f);
            if (PACKED) {
                acc_seg(z, XL + b * 1028 + kc * 128,
                        (const float4*)pDU1 + (size_t)dcol * 512 + kc * 128, 128);
                acc_seg(z, XL + b * 1028 + 512 + kc * 128,
                        (const float4*)pDW1 + (size_t)dcol * 512 + kc * 128, 128);
            } else {
                acc_segS(z, XL + b * 1028 + kc * 128, pDU1, kc * 128, 128, dcol);
                acc_segS(z, XL + b * 1028 + 512 + kc * 128, pDW1, kc * 128, 128, dcol);
            }
            reduce4(z);
            if (lane < 16) {
                float c2;
                float h2 = lstm_fin(z, db1, dcol, c_car, c2);
                c_car = c2;
                st_coh(&HT[cur ^ 1][(size_t)dcol * Bsz + bgl], h2);
            }
        }
        arrive(&gslots[gm], ++ep);
        cur ^= 1;
    }

    // ---- final: out_127 -> row 0 ----
    wait_grp(gslots, ep);
    stage_coh_T(XL, 516, 0, HT[cur], row0);
    __syncthreads();
    out_part(XL, 516, ORED, b, kc, w, fcol, pDWT);
    __syncthreads();
    if (tid < 64) {
        const int bb = tid >> 2, ff = tid & 3;
        const int fc = grp * 16 + dslc * 4 + ff;
        const float* r = ORED + bb * 16 + ff * 4;
        float s = r[0] + r[1] + r[2] + r[3] + db_[fc];
        out[((size_t)(row0 + bb) * Tsz + 0) * Fsz + fc] = s;
    }
}

extern "C" void kernel_launch(void* const* d_in, const int* in_sizes, int n_in,
                              void* d_out, int out_size, void* d_ws, size_t ws_size,
                              hipStream_t stream) {
    (void)in_sizes; (void)n_in; (void)out_size;
    const float* enc_in = (const float*)d_in[0];
    const float* dec_in = (const float*)d_in[1];
    const float* eW0 = (const float*)d_in[2];
    const float* eU0 = (const float*)d_in[3];
    const float* eb0 = (const float*)d_in[4];
    const float* eW1 = (const float*)d_in[5];
    const float* eU1 = (const float*)d_in[6];
    const float* eb1 = (const float*)d_in[7];
    const float* dW0 = (const float*)d_in[8];
    const float* dU0 = (const float*)d_in[9];
    const float* db0 = (const float*)d_in[10];
    const float* dW1 = (const float*)d_in[11];
    const float* dU1 = (const float*)d_in[12];
    const float* db1 = (const float*)d_in[13];
    const float* dw  = (const float*)d_in[14];
    const float* db_ = (const float*)d_in[15];
    float* out = (float*)d_out;
    float* ws = (float*)d_ws;

    // zero: all barrier slots + HT0 (initial h = 0)
    hipMemsetAsync(d_ws, 0, (size_t)(OFF_HT0 + Dsz * Bsz) * sizeof(float), stream);

    const bool packed = ws_size >= (size_t)WS_PACKED_FLOATS * sizeof(float);
    if (packed)
        lstm_ae_kernel<true><<<NBLK, NTHR, 0, stream>>>(
            enc_in, dec_in, eW0, eU0, eb0, eW1, eU1, eb1,
            dW0, dU0, db0, dW1, dU1, db1, dw, db_, out, ws);
    else
        lstm_ae_kernel<false><<<NBLK, NTHR, 0, stream>>>(
            enc_in, dec_in, eW0, eU0, eb0, eW1, eU1, eb1,
            dW0, dU0, db0, dW1, dU1, db1, dw, db_, out, ws);
}